// Round 3
// baseline (739.004 us; speedup 1.0000x reference)
//
#include <hip/hip_runtime.h>
#include <stdint.h>

using f16 = _Float16;
typedef __attribute__((ext_vector_type(8))) f16 f16x8;
typedef __attribute__((ext_vector_type(4))) float f32x4;

constexpr int N = 1024;

__device__ __forceinline__ float leaky(float v) { return v >= 0.f ? v : 0.01f * v; }

__device__ __forceinline__ void dma16(const void* g, void* l) {
    __builtin_amdgcn_global_load_lds(
        (const __attribute__((address_space(1))) uint32_t*)g,
        (__attribute__((address_space(3))) uint32_t*)l, 16, 0, 0);
}

// ---------------------------------------------------------------------------
// Phase A: BinaryTreeConv  Yc^T[n][o] = sum_kap Xg[n][kap] * Wfc[kap][o] + bc
// Tile: 64 nodes x CO, 4 waves (2 n-groups x 2 o-groups).
// K staged in chunks of CK kap (CK | CI), double-buffered, rotation-swizzled
// rows so ds_read_b128 fragments stay <=2-way bank aliased. DMA granule
// mapping: LDS granule G -> row G/S, slot G%S, kap byte = ((slot-(row&7)) mod S)*16.
// ---------------------------------------------------------------------------
template<int CI, int CO, int CK>
__global__ __launch_bounds__(256) void convA_kernel(
    const f16* __restrict__ X, const int* __restrict__ idx,
    const f16* __restrict__ Wf, const float* __restrict__ bc,
    f16* __restrict__ yc, float2* __restrict__ part)
{
    constexpr int T = 3 * CI / CK;       // chunks
    constexpr int U = CO / 16, UW = CO / 32;
    constexpr int S = CK / 8;            // 16B slots per row
    constexpr int P = 2 * CK;            // row pitch bytes
    constexpr int NG = CK / 32;          // dma16 per thread per chunk
    constexpr int BUF = 64 * CK * 2;     // bytes per buffer

    __shared__ alignas(16) f16 stage[2 * 64 * CK];
    __shared__ float redu[8];

    const int tid = threadIdx.x;
    const int w = tid >> 6, l = tid & 63;
    const int wn = w & 1, wo = w >> 1;
    const int n0 = blockIdx.x * 64;
    const int b = blockIdx.y;

    // granule geometry for this thread's NG dma calls
    int rrow[NG], kapb[NG];
    #pragma unroll
    for (int r = 0; r < NG; ++r) {
        int G = w * (NG * 64) + r * 64 + l;
        rrow[r] = G / S;
        int cs = G % S - (rrow[r] & 7);
        if (cs < 0) cs += S;
        kapb[r] = cs * 8;
    }
    const int ib = b * 3 * N + 3 * n0;
    const char* xb = (const char*)(X + (size_t)b * N * CI);
    char* sbase = (char*)stage;
    char* dstb = sbase + w * (NG * 1024);

    auto stage_chunk = [&](int t) {
        #pragma unroll
        for (int r = 0; r < NG; ++r) {
            int kg = t * CK + kapb[r];
            int seg = kg / CI;
            int cof = kg - seg * CI;
            int row = idx[ib + 3 * rrow[r] + seg];
            dma16(xb + ((size_t)row * CI + cof) * 2, dstb + (t & 1) * BUF + r * 1024);
        }
    };

    int rowb[2], rot[2];
    #pragma unroll
    for (int rt = 0; rt < 2; ++rt) {
        int rr = 32 * wn + 16 * rt + (l & 15);
        rowb[rt] = rr * P;
        rot[rt] = (l >> 4) + (rr & 7);
    }

    f32x4 acc[2][UW] = {};
    stage_chunk(0);
    __syncthreads();

    for (int t = 0; t < T; ++t) {
        if (t + 1 < T) stage_chunk(t + 1);
        const char* sb = sbase + (t & 1) * BUF;
        #pragma unroll
        for (int s = 0; s < CK / 32; ++s) {
            f16x8 a0, a1;
            {
                int sl = 4 * s + rot[0]; if (sl >= S) sl -= S;
                a0 = *(const f16x8*)(sb + rowb[0] + sl * 16);
            }
            {
                int sl = 4 * s + rot[1]; if (sl >= S) sl -= S;
                a1 = *(const f16x8*)(sb + rowb[1] + sl * 16);
            }
            const int skk = t * (CK / 32) + s;
            #pragma unroll
            for (int uu = 0; uu < UW; ++uu) {
                f16x8 wv = *(const f16x8*)(Wf + (((size_t)skk * U + wo * UW + uu) * 64 + l) * 8);
                acc[0][uu] = __builtin_amdgcn_mfma_f32_16x16x32_f16(a0, wv, acc[0][uu], 0, 0, 0);
                acc[1][uu] = __builtin_amdgcn_mfma_f32_16x16x32_f16(a1, wv, acc[1][uu], 0, 0, 0);
            }
        }
        __syncthreads();
    }

    // epilogue: bias, store f16, per-tree stats partials
    float p1 = 0.f, p2 = 0.f;
    #pragma unroll
    for (int rt = 0; rt < 2; ++rt) {
        #pragma unroll
        for (int uu = 0; uu < UW; ++uu) {
            int o = wo * (CO / 2) + uu * 16 + (l & 15);
            float bcv = bc[o];
            size_t rb = ((size_t)b * N + (n0 + 32 * wn + 16 * rt + 4 * (l >> 4))) * CO + o;
            #pragma unroll
            for (int j = 0; j < 4; ++j) {
                float v = acc[rt][uu][j] + bcv;
                yc[rb + (size_t)j * CO] = (f16)v;
                p1 += v; p2 += v * v;
            }
        }
    }
    #pragma unroll
    for (int m = 32; m; m >>= 1) { p1 += __shfl_xor(p1, m); p2 += __shfl_xor(p2, m); }
    if (l == 0) { redu[w * 2] = p1; redu[w * 2 + 1] = p2; }
    __syncthreads();
    if (tid == 0)
        part[(size_t)b * 16 + blockIdx.x] =
            make_float2(redu[0] + redu[2] + redu[4] + redu[6],
                        redu[1] + redu[3] + redu[5] + redu[7]);
}

__global__ __launch_bounds__(64) void reduce_stats_kernel(
    const float2* __restrict__ part, float2* __restrict__ stats, int nparts, float Mf)
{
    int b = blockIdx.x;
    float s1 = 0.f, s2 = 0.f;
    for (int i = threadIdx.x; i < nparts; i += 64) {
        float2 p = part[(size_t)b * nparts + i];
        s1 += p.x; s2 += p.y;
    }
    #pragma unroll
    for (int m = 32; m; m >>= 1) { s1 += __shfl_xor(s1, m); s2 += __shfl_xor(s2, m); }
    if (threadIdx.x == 0) {
        float mu = s1 / Mf;
        float var = (s2 - s1 * s1 / Mf) / (Mf - 1.f);   // ddof = 1
        var = fmaxf(var, 0.f);
        stats[b] = make_float2(mu, 1.f / (sqrtf(var) + 1e-5f));
    }
}

// ---------------------------------------------------------------------------
// Phase B: ChannelMixer GEMM (K = CI, identity rows, no gather); whole K fits
// LDS -> single staging pass, ONE barrier, then pure MFMA. TreeLayerNorm +
// leaky fused into the epilogue: x = leaky(ym + (yc-mu)*inv), in place.
// ---------------------------------------------------------------------------
template<int CI, int CO>
__global__ __launch_bounds__(256) void mixB_kernel(
    const f16* __restrict__ X, const f16* __restrict__ Wf, const float* __restrict__ bm,
    f16* __restrict__ y, const float2* __restrict__ stats)
{
    constexpr int U = CO / 16, UW = CO / 32;
    constexpr int S = CI / 8;
    constexpr int P = 2 * CI;
    constexpr int NG = CI / 32;

    __shared__ alignas(16) f16 stage[64 * CI];

    const int tid = threadIdx.x;
    const int w = tid >> 6, l = tid & 63;
    const int wn = w & 1, wo = w >> 1;
    const int n0 = blockIdx.x * 64;
    const int b = blockIdx.y;

    const char* xb = (const char*)(X + (size_t)b * N * CI);
    char* sbase = (char*)stage;
    char* dstb = sbase + w * (NG * 1024);

    #pragma unroll
    for (int r = 0; r < NG; ++r) {
        int G = w * (NG * 64) + r * 64 + l;
        int rr = G / S;
        int cs = G % S - (rr & 7);
        if (cs < 0) cs += S;
        dma16(xb + ((size_t)(n0 + rr) * CI + cs * 8) * 2, dstb + r * 1024);
    }

    int rowb[2], rot[2];
    #pragma unroll
    for (int rt = 0; rt < 2; ++rt) {
        int rr = 32 * wn + 16 * rt + (l & 15);
        rowb[rt] = rr * P;
        rot[rt] = (l >> 4) + (rr & 7);
    }

    f32x4 acc[2][UW] = {};
    __syncthreads();

    #pragma unroll
    for (int s = 0; s < CI / 32; ++s) {
        f16x8 a0, a1;
        {
            int sl = 4 * s + rot[0]; if (sl >= S) sl -= S;
            a0 = *(const f16x8*)(sbase + rowb[0] + sl * 16);
        }
        {
            int sl = 4 * s + rot[1]; if (sl >= S) sl -= S;
            a1 = *(const f16x8*)(sbase + rowb[1] + sl * 16);
        }
        #pragma unroll
        for (int uu = 0; uu < UW; ++uu) {
            f16x8 wv = *(const f16x8*)(Wf + (((size_t)s * U + wo * UW + uu) * 64 + l) * 8);
            acc[0][uu] = __builtin_amdgcn_mfma_f32_16x16x32_f16(a0, wv, acc[0][uu], 0, 0, 0);
            acc[1][uu] = __builtin_amdgcn_mfma_f32_16x16x32_f16(a1, wv, acc[1][uu], 0, 0, 0);
        }
    }

    const float2 st = stats[b];
    #pragma unroll
    for (int rt = 0; rt < 2; ++rt) {
        #pragma unroll
        for (int uu = 0; uu < UW; ++uu) {
            int o = wo * (CO / 2) + uu * 16 + (l & 15);
            float bmv = bm[o];
            size_t rb = ((size_t)b * N + (n0 + 32 * wn + 16 * rt + 4 * (l >> 4))) * CO + o;
            #pragma unroll
            for (int j = 0; j < 4; ++j) {
                size_t off = rb + (size_t)j * CO;
                float ycv = (float)y[off];
                float v = acc[rt][uu][j] + bmv + (ycv - st.x) * st.y;
                y[off] = (f16)leaky(v);
            }
        }
    }
}

// fp32 [B][160][N] -> f16 [B][N][160]
__global__ __launch_bounds__(256) void transpose_kernel(
    const float* __restrict__ trees, f16* __restrict__ X0)
{
    __shared__ f16 tile[32][66];
    int b = blockIdx.z, c0 = blockIdx.y * 32, n0 = blockIdx.x * 64;
    int tid = threadIdx.x;
    int nl = tid & 63, c4 = tid >> 6;
    #pragma unroll
    for (int cc = 0; cc < 8; ++cc) {
        int c = c4 * 8 + cc;
        tile[c][nl] = (f16)trees[((size_t)b * 160 + c0 + c) * N + n0 + nl];
    }
    __syncthreads();
    int nn = tid >> 2, gc = tid & 3;
    f16x8 pack;
    #pragma unroll
    for (int e = 0; e < 8; ++e) pack[e] = tile[gc * 8 + e][nn];
    *(f16x8*)(X0 + ((size_t)b * N + n0 + nn) * 160 + c0 + gc * 8) = pack;
}

// weights -> fragment-ready f16 layout: elem ((t*U+u)*64+l)*8+j  holds
// W[kap = 32t+8*(l>>4)+j][o = 16u+(l&15)], kappa-order kap = k*CI + c.
__global__ __launch_bounds__(256) void prepW_kernel(
    const float* __restrict__ Wsrc, f16* __restrict__ out,
    int K, int CO, int CI, int isconv)
{
    int e = blockIdx.x * 256 + threadIdx.x;
    if (e >= K * CO) return;
    int j = e & 7, l = (e >> 3) & 63, r = e >> 9;
    int U = CO / 16;
    int u = r % U, t = r / U;
    int kap = 32 * t + 8 * (l >> 4) + j;
    int o = 16 * u + (l & 15);
    float v = isconv ? Wsrc[((size_t)o * CI + (kap % CI)) * 3 + kap / CI]
                     : Wsrc[(size_t)o * CI + kap];
    out[e] = (f16)v;
}

// masked max-pool over valid nodes + 64->32->1 MLP; x3 is [b][n][64] f16.
__global__ __launch_bounds__(256) void final_kernel(
    const f16* __restrict__ x3, const int* __restrict__ nodes,
    const float* __restrict__ W1, const float* __restrict__ b1,
    const float* __restrict__ W2, const float* __restrict__ b2,
    float* __restrict__ out)
{
    int b = blockIdx.x, tid = threadIdx.x;
    int o = tid & 63, r = tid >> 6;
    int nv = nodes[b];
    const f16* p = x3 + (size_t)b * N * 64 + o;
    float mx = -3.4e38f;
    for (int n = r; n < nv; n += 4) mx = fmaxf(mx, (float)p[(size_t)n * 64]);
    __shared__ float pool[4][64];
    __shared__ float pooled[64], hbuf[32];
    pool[r][o] = mx;
    __syncthreads();
    if (tid < 64) pooled[tid] = fmaxf(fmaxf(pool[0][tid], pool[1][tid]),
                                      fmaxf(pool[2][tid], pool[3][tid]));
    __syncthreads();
    if (tid < 32) {
        float h = b1[tid];
        #pragma unroll 8
        for (int oo = 0; oo < 64; ++oo) h += pooled[oo] * W1[oo * 32 + tid];
        hbuf[tid] = leaky(h);
    }
    __syncthreads();
    if (tid == 0) {
        float rr = b2[0];
        for (int jj = 0; jj < 32; ++jj) rr += hbuf[jj] * W2[jj];
        out[b] = rr;
    }
}

extern "C" void kernel_launch(void* const* d_in, const int* in_sizes, int n_in,
                              void* d_out, int out_size, void* d_ws, size_t ws_size,
                              hipStream_t stream)
{
    (void)in_sizes; (void)n_in; (void)out_size; (void)ws_size;
    const float* trees = (const float*)d_in[0];
    const int* indexes = (const int*)d_in[1];
    const int* nodes   = (const int*)d_in[2];
    const float* Wc1 = (const float*)d_in[3];
    const float* bc1 = (const float*)d_in[4];
    const float* Wm1 = (const float*)d_in[5];
    const float* bm1 = (const float*)d_in[6];
    const float* Wc2 = (const float*)d_in[7];
    const float* bc2 = (const float*)d_in[8];
    const float* Wm2 = (const float*)d_in[9];
    const float* bm2 = (const float*)d_in[10];
    const float* Wc3 = (const float*)d_in[11];
    const float* bc3 = (const float*)d_in[12];
    const float* Wm3 = (const float*)d_in[13];
    const float* bm3 = (const float*)d_in[14];
    const float* W1 = (const float*)d_in[15];
    const float* b1 = (const float*)d_in[16];
    const float* W2 = (const float*)d_in[17];
    const float* b2 = (const float*)d_in[18];
    float* out = (float*)d_out;

    // ws layout:
    //   [0, 83886080)            X0 [B][N][160] f16      -> later yc2/x2 (67MB)
    //   [83886080, 218103808)    yc1/x1 [B][N][256] f16  -> later yc3/x3 (33.5MB)
    //   [218103808, ...)         Wfrags, parts, stats
    char* ws = (char*)d_ws;
    f16* X0 = (f16*)ws;
    f16* A1 = (f16*)(ws + 83886080);
    f16* A2 = (f16*)ws;
    f16* A3 = A1;
    size_t toff = 218103808;
    f16* Wfc1 = (f16*)(ws + toff); toff += (size_t)480 * 256 * 2;
    f16* Wfm1 = (f16*)(ws + toff); toff += (size_t)160 * 256 * 2;
    f16* Wfc2 = (f16*)(ws + toff); toff += (size_t)768 * 128 * 2;
    f16* Wfm2 = (f16*)(ws + toff); toff += (size_t)256 * 128 * 2;
    f16* Wfc3 = (f16*)(ws + toff); toff += (size_t)384 * 64 * 2;
    f16* Wfm3 = (f16*)(ws + toff); toff += (size_t)128 * 64 * 2;
    float2* part  = (float2*)(ws + toff); toff += (size_t)256 * 16 * 8;
    float2* stats = (float2*)(ws + toff);

    transpose_kernel<<<dim3(16, 5, 256), 256, 0, stream>>>(trees, X0);
    prepW_kernel<<<480 * 256 / 256, 256, 0, stream>>>(Wc1, Wfc1, 480, 256, 160, 1);
    prepW_kernel<<<160 * 256 / 256, 256, 0, stream>>>(Wm1, Wfm1, 160, 256, 160, 0);
    prepW_kernel<<<768 * 128 / 256, 256, 0, stream>>>(Wc2, Wfc2, 768, 128, 256, 1);
    prepW_kernel<<<256 * 128 / 256, 256, 0, stream>>>(Wm2, Wfm2, 256, 128, 256, 0);
    prepW_kernel<<<384 * 64 / 256, 256, 0, stream>>>(Wc3, Wfc3, 384, 64, 128, 1);
    prepW_kernel<<<128 * 64 / 256, 256, 0, stream>>>(Wm3, Wfm3, 128, 64, 128, 0);

    convA_kernel<160, 256, 160><<<dim3(16, 256), 256, 0, stream>>>(X0, indexes, Wfc1, bc1, A1, part);
    reduce_stats_kernel<<<256, 64, 0, stream>>>(part, stats, 16, 262144.f);
    mixB_kernel<160, 256><<<dim3(16, 256), 256, 0, stream>>>(X0, Wfm1, bm1, A1, stats);

    convA_kernel<256, 128, 128><<<dim3(16, 256), 256, 0, stream>>>(A1, indexes, Wfc2, bc2, A2, part);
    reduce_stats_kernel<<<256, 64, 0, stream>>>(part, stats, 16, 131072.f);
    mixB_kernel<256, 128><<<dim3(16, 256), 256, 0, stream>>>(A1, Wfm2, bm2, A2, stats);

    convA_kernel<128, 64, 128><<<dim3(16, 256), 256, 0, stream>>>(A2, indexes, Wfc3, bc3, A3, part);
    reduce_stats_kernel<<<256, 64, 0, stream>>>(part, stats, 16, 65536.f);
    mixB_kernel<128, 64><<<dim3(16, 256), 256, 0, stream>>>(A2, Wfm3, bm3, A3, stats);

    final_kernel<<<256, 256, 0, stream>>>(A3, nodes, W1, b1, W2, b2, out);
}

// Round 4
// 637.908 us; speedup vs baseline: 1.1585x; 1.1585x over previous
//
#include <hip/hip_runtime.h>
#include <stdint.h>

using f16 = _Float16;
typedef __attribute__((ext_vector_type(8))) f16 f16x8;
typedef __attribute__((ext_vector_type(4))) float f32x4;

constexpr int N = 1024;

__device__ __forceinline__ float leaky(float v) { return v >= 0.f ? v : 0.01f * v; }

__device__ __forceinline__ void dma16(const void* g, void* l) {
    __builtin_amdgcn_global_load_lds(
        (const __attribute__((address_space(1))) uint32_t*)g,
        (__attribute__((address_space(3))) uint32_t*)l, 16, 0, 0);
}

// ---------------------------------------------------------------------------
// Phase A: BinaryTreeConv  Yc^T[n][o] = sum_kap Xg[n][kap] * Wfc[kap][o] + bc
// Tile: 64 nodes x CO, 4 waves (2 n-groups x 2 o-groups).
// K in chunks of CK (CK | CI -> chunk's segment is compile-time), TRIPLE
// buffered, one raw s_barrier per chunk with counted s_waitcnt vmcnt(NG):
// next chunk's global_load_lds stay in flight across the barrier.
// All idx reads hoisted to kernel start -> staging is pure dma16 issue.
// Rotation swizzle keeps ds_read_b128 fragments <=2-way bank aliased.
// ---------------------------------------------------------------------------
template<int CI, int CO, int CK>
__global__ __launch_bounds__(256) void convA_kernel(
    const f16* __restrict__ X, const int* __restrict__ idx,
    const f16* __restrict__ Wf, const float* __restrict__ bc,
    f16* __restrict__ yc, float2* __restrict__ part)
{
    constexpr int T = 3 * CI / CK;       // chunks
    constexpr int U = CO / 16, UW = CO / 32;
    constexpr int S = CK / 8;            // 16B slots per row
    constexpr int P = 2 * CK;            // row pitch bytes
    constexpr int NG = CK / 32;          // dma16 per thread per chunk
    constexpr int BUF = 64 * CK * 2;     // bytes per buffer

    __shared__ alignas(16) f16 stage[3 * 64 * CK];
    __shared__ float redu[8];

    const int tid = threadIdx.x;
    const int w = tid >> 6, l = tid & 63;
    const int wn = w & 1, wo = w >> 1;
    const int n0 = blockIdx.x * 64;
    const int b = blockIdx.y;

    // granule geometry + hoisted gather indices (all segments, once)
    int kapb[NG];            // rotated kap element offset within chunk
    int rows[NG][3];         // gather node index per (granule, segment)
    {
        const int ib = b * 3 * N + 3 * n0;
        #pragma unroll
        for (int r = 0; r < NG; ++r) {
            int G = w * (NG * 64) + r * 64 + l;
            int rrow = G / S;
            int cs = G % S - (rrow & 7);
            if (cs < 0) cs += S;
            kapb[r] = cs * 8;
            #pragma unroll
            for (int seg = 0; seg < 3; ++seg)
                rows[r][seg] = idx[ib + 3 * rrow + seg];
        }
    }
    const char* xb = (const char*)(X + (size_t)b * N * CI);
    char* sbase = (char*)stage;

    // stage chunk t into buffer t%3 (t compile-time via full unroll)
    auto stage_chunk = [&](int t) {
        char* dstb = sbase + (t % 3) * BUF + w * (NG * 1024);
        #pragma unroll
        for (int r = 0; r < NG; ++r) {
            int seg = (t * CK) / CI;                      // compile-time
            int cof = t * CK - seg * CI + kapb[r];
            dma16(xb + ((size_t)rows[r][seg] * CI + cof) * 2, dstb + r * 1024);
        }
    };

    int rowb[2], rot[2];
    #pragma unroll
    for (int rt = 0; rt < 2; ++rt) {
        int rr = 32 * wn + 16 * rt + (l & 15);
        rowb[rt] = rr * P;
        rot[rt] = (l >> 4) + (rr & 7);
    }

    f32x4 acc[2][UW] = {};
    stage_chunk(0);

    #pragma unroll
    for (int t = 0; t < T; ++t) {
        if (t + 1 < T) stage_chunk(t + 1);
        if (t + 1 < T) asm volatile("s_waitcnt vmcnt(%0)" :: "n"(NG) : "memory");
        else           asm volatile("s_waitcnt vmcnt(0)" ::: "memory");
        __builtin_amdgcn_s_barrier();
        __builtin_amdgcn_sched_barrier(0);
        const char* sb = sbase + (t % 3) * BUF;
        #pragma unroll
        for (int s = 0; s < CK / 32; ++s) {
            f16x8 a0, a1;
            {
                int sl = 4 * s + rot[0]; if (sl >= S) sl -= S;
                a0 = *(const f16x8*)(sb + rowb[0] + sl * 16);
            }
            {
                int sl = 4 * s + rot[1]; if (sl >= S) sl -= S;
                a1 = *(const f16x8*)(sb + rowb[1] + sl * 16);
            }
            const int skk = t * (CK / 32) + s;
            #pragma unroll
            for (int uu = 0; uu < UW; ++uu) {
                f16x8 wv = *(const f16x8*)(Wf + (((size_t)skk * U + wo * UW + uu) * 64 + l) * 8);
                acc[0][uu] = __builtin_amdgcn_mfma_f32_16x16x32_f16(a0, wv, acc[0][uu], 0, 0, 0);
                acc[1][uu] = __builtin_amdgcn_mfma_f32_16x16x32_f16(a1, wv, acc[1][uu], 0, 0, 0);
            }
        }
        __builtin_amdgcn_s_barrier();    // all reads of buf t%3 done before reuse
    }

    // epilogue: bias, store f16, per-tree stats partials
    float p1 = 0.f, p2 = 0.f;
    #pragma unroll
    for (int rt = 0; rt < 2; ++rt) {
        #pragma unroll
        for (int uu = 0; uu < UW; ++uu) {
            int o = wo * (CO / 2) + uu * 16 + (l & 15);
            float bcv = bc[o];
            size_t rb = ((size_t)b * N + (n0 + 32 * wn + 16 * rt + 4 * (l >> 4))) * CO + o;
            #pragma unroll
            for (int j = 0; j < 4; ++j) {
                float v = acc[rt][uu][j] + bcv;
                yc[rb + (size_t)j * CO] = (f16)v;
                p1 += v; p2 += v * v;
            }
        }
    }
    #pragma unroll
    for (int m = 32; m; m >>= 1) { p1 += __shfl_xor(p1, m); p2 += __shfl_xor(p2, m); }
    if (l == 0) { redu[w * 2] = p1; redu[w * 2 + 1] = p2; }
    __syncthreads();
    if (tid == 0)
        part[(size_t)b * 16 + blockIdx.x] =
            make_float2(redu[0] + redu[2] + redu[4] + redu[6],
                        redu[1] + redu[3] + redu[5] + redu[7]);
}

__global__ __launch_bounds__(64) void reduce_stats_kernel(
    const float2* __restrict__ part, float2* __restrict__ stats, int nparts, float Mf)
{
    int b = blockIdx.x;
    float s1 = 0.f, s2 = 0.f;
    for (int i = threadIdx.x; i < nparts; i += 64) {
        float2 p = part[(size_t)b * nparts + i];
        s1 += p.x; s2 += p.y;
    }
    #pragma unroll
    for (int m = 32; m; m >>= 1) { s1 += __shfl_xor(s1, m); s2 += __shfl_xor(s2, m); }
    if (threadIdx.x == 0) {
        float mu = s1 / Mf;
        float var = (s2 - s1 * s1 / Mf) / (Mf - 1.f);   // ddof = 1
        var = fmaxf(var, 0.f);
        stats[b] = make_float2(mu, 1.f / (sqrtf(var) + 1e-5f));
    }
}

// ---------------------------------------------------------------------------
// Phase B: ChannelMixer GEMM (K = CI, identity rows, no gather); whole K fits
// LDS -> single staging pass, ONE barrier, then pure MFMA. TreeLayerNorm +
// leaky fused into the epilogue: x = leaky(ym + (yc-mu)*inv), in place.
// ---------------------------------------------------------------------------
template<int CI, int CO>
__global__ __launch_bounds__(256) void mixB_kernel(
    const f16* __restrict__ X, const f16* __restrict__ Wf, const float* __restrict__ bm,
    f16* __restrict__ y, const float2* __restrict__ stats)
{
    constexpr int U = CO / 16, UW = CO / 32;
    constexpr int S = CI / 8;
    constexpr int P = 2 * CI;
    constexpr int NG = CI / 32;

    __shared__ alignas(16) f16 stage[64 * CI];

    const int tid = threadIdx.x;
    const int w = tid >> 6, l = tid & 63;
    const int wn = w & 1, wo = w >> 1;
    const int n0 = blockIdx.x * 64;
    const int b = blockIdx.y;

    const char* xb = (const char*)(X + (size_t)b * N * CI);
    char* sbase = (char*)stage;
    char* dstb = sbase + w * (NG * 1024);

    #pragma unroll
    for (int r = 0; r < NG; ++r) {
        int G = w * (NG * 64) + r * 64 + l;
        int rr = G / S;
        int cs = G % S - (rr & 7);
        if (cs < 0) cs += S;
        dma16(xb + ((size_t)(n0 + rr) * CI + cs * 8) * 2, dstb + r * 1024);
    }

    int rowb[2], rot[2];
    #pragma unroll
    for (int rt = 0; rt < 2; ++rt) {
        int rr = 32 * wn + 16 * rt + (l & 15);
        rowb[rt] = rr * P;
        rot[rt] = (l >> 4) + (rr & 7);
    }

    f32x4 acc[2][UW] = {};
    __syncthreads();

    #pragma unroll
    for (int s = 0; s < CI / 32; ++s) {
        f16x8 a0, a1;
        {
            int sl = 4 * s + rot[0]; if (sl >= S) sl -= S;
            a0 = *(const f16x8*)(sbase + rowb[0] + sl * 16);
        }
        {
            int sl = 4 * s + rot[1]; if (sl >= S) sl -= S;
            a1 = *(const f16x8*)(sbase + rowb[1] + sl * 16);
        }
        #pragma unroll
        for (int uu = 0; uu < UW; ++uu) {
            f16x8 wv = *(const f16x8*)(Wf + (((size_t)s * U + wo * UW + uu) * 64 + l) * 8);
            acc[0][uu] = __builtin_amdgcn_mfma_f32_16x16x32_f16(a0, wv, acc[0][uu], 0, 0, 0);
            acc[1][uu] = __builtin_amdgcn_mfma_f32_16x16x32_f16(a1, wv, acc[1][uu], 0, 0, 0);
        }
    }

    const float2 st = stats[b];
    #pragma unroll
    for (int rt = 0; rt < 2; ++rt) {
        #pragma unroll
        for (int uu = 0; uu < UW; ++uu) {
            int o = wo * (CO / 2) + uu * 16 + (l & 15);
            float bmv = bm[o];
            size_t rb = ((size_t)b * N + (n0 + 32 * wn + 16 * rt + 4 * (l >> 4))) * CO + o;
            #pragma unroll
            for (int j = 0; j < 4; ++j) {
                size_t off = rb + (size_t)j * CO;
                float ycv = (float)y[off];
                float v = acc[rt][uu][j] + bmv + (ycv - st.x) * st.y;
                y[off] = (f16)leaky(v);
            }
        }
    }
}

// fp32 [B][160][N] -> f16 [B][N][160]
__global__ __launch_bounds__(256) void transpose_kernel(
    const float* __restrict__ trees, f16* __restrict__ X0)
{
    __shared__ f16 tile[32][66];
    int b = blockIdx.z, c0 = blockIdx.y * 32, n0 = blockIdx.x * 64;
    int tid = threadIdx.x;
    int nl = tid & 63, c4 = tid >> 6;
    #pragma unroll
    for (int cc = 0; cc < 8; ++cc) {
        int c = c4 * 8 + cc;
        tile[c][nl] = (f16)trees[((size_t)b * 160 + c0 + c) * N + n0 + nl];
    }
    __syncthreads();
    int nn = tid >> 2, gc = tid & 3;
    f16x8 pack;
    #pragma unroll
    for (int e = 0; e < 8; ++e) pack[e] = tile[gc * 8 + e][nn];
    *(f16x8*)(X0 + ((size_t)b * N + n0 + nn) * 160 + c0 + gc * 8) = pack;
}

// weights -> fragment-ready f16 layout: elem ((t*U+u)*64+l)*8+j  holds
// W[kap = 32t+8*(l>>4)+j][o = 16u+(l&15)], kappa-order kap = k*CI + c.
__global__ __launch_bounds__(256) void prepW_kernel(
    const float* __restrict__ Wsrc, f16* __restrict__ out,
    int K, int CO, int CI, int isconv)
{
    int e = blockIdx.x * 256 + threadIdx.x;
    if (e >= K * CO) return;
    int j = e & 7, l = (e >> 3) & 63, r = e >> 9;
    int U = CO / 16;
    int u = r % U, t = r / U;
    int kap = 32 * t + 8 * (l >> 4) + j;
    int o = 16 * u + (l & 15);
    float v = isconv ? Wsrc[((size_t)o * CI + (kap % CI)) * 3 + kap / CI]
                     : Wsrc[(size_t)o * CI + kap];
    out[e] = (f16)v;
}

// masked max-pool over valid nodes + 64->32->1 MLP; x3 is [b][n][64] f16.
__global__ __launch_bounds__(256) void final_kernel(
    const f16* __restrict__ x3, const int* __restrict__ nodes,
    const float* __restrict__ W1, const float* __restrict__ b1,
    const float* __restrict__ W2, const float* __restrict__ b2,
    float* __restrict__ out)
{
    int b = blockIdx.x, tid = threadIdx.x;
    int o = tid & 63, r = tid >> 6;
    int nv = nodes[b];
    const f16* p = x3 + (size_t)b * N * 64 + o;
    float mx = -3.4e38f;
    for (int n = r; n < nv; n += 4) mx = fmaxf(mx, (float)p[(size_t)n * 64]);
    __shared__ float pool[4][64];
    __shared__ float pooled[64], hbuf[32];
    pool[r][o] = mx;
    __syncthreads();
    if (tid < 64) pooled[tid] = fmaxf(fmaxf(pool[0][tid], pool[1][tid]),
                                      fmaxf(pool[2][tid], pool[3][tid]));
    __syncthreads();
    if (tid < 32) {
        float h = b1[tid];
        #pragma unroll 8
        for (int oo = 0; oo < 64; ++oo) h += pooled[oo] * W1[oo * 32 + tid];
        hbuf[tid] = leaky(h);
    }
    __syncthreads();
    if (tid == 0) {
        float rr = b2[0];
        for (int jj = 0; jj < 32; ++jj) rr += hbuf[jj] * W2[jj];
        out[b] = rr;
    }
}

extern "C" void kernel_launch(void* const* d_in, const int* in_sizes, int n_in,
                              void* d_out, int out_size, void* d_ws, size_t ws_size,
                              hipStream_t stream)
{
    (void)in_sizes; (void)n_in; (void)out_size; (void)ws_size;
    const float* trees = (const float*)d_in[0];
    const int* indexes = (const int*)d_in[1];
    const int* nodes   = (const int*)d_in[2];
    const float* Wc1 = (const float*)d_in[3];
    const float* bc1 = (const float*)d_in[4];
    const float* Wm1 = (const float*)d_in[5];
    const float* bm1 = (const float*)d_in[6];
    const float* Wc2 = (const float*)d_in[7];
    const float* bc2 = (const float*)d_in[8];
    const float* Wm2 = (const float*)d_in[9];
    const float* bm2 = (const float*)d_in[10];
    const float* Wc3 = (const float*)d_in[11];
    const float* bc3 = (const float*)d_in[12];
    const float* Wm3 = (const float*)d_in[13];
    const float* bm3 = (const float*)d_in[14];
    const float* W1 = (const float*)d_in[15];
    const float* b1 = (const float*)d_in[16];
    const float* W2 = (const float*)d_in[17];
    const float* b2 = (const float*)d_in[18];
    float* out = (float*)d_out;

    // ws layout:
    //   [0, 83886080)            X0 [B][N][160] f16      -> later yc2/x2 (67MB)
    //   [83886080, 218103808)    yc1/x1 [B][N][256] f16  -> later yc3/x3 (33.5MB)
    //   [218103808, ...)         Wfrags, parts, stats
    char* ws = (char*)d_ws;
    f16* X0 = (f16*)ws;
    f16* A1 = (f16*)(ws + 83886080);
    f16* A2 = (f16*)ws;
    f16* A3 = A1;
    size_t toff = 218103808;
    f16* Wfc1 = (f16*)(ws + toff); toff += (size_t)480 * 256 * 2;
    f16* Wfm1 = (f16*)(ws + toff); toff += (size_t)160 * 256 * 2;
    f16* Wfc2 = (f16*)(ws + toff); toff += (size_t)768 * 128 * 2;
    f16* Wfm2 = (f16*)(ws + toff); toff += (size_t)256 * 128 * 2;
    f16* Wfc3 = (f16*)(ws + toff); toff += (size_t)384 * 64 * 2;
    f16* Wfm3 = (f16*)(ws + toff); toff += (size_t)128 * 64 * 2;
    float2* part  = (float2*)(ws + toff); toff += (size_t)256 * 16 * 8;
    float2* stats = (float2*)(ws + toff);

    transpose_kernel<<<dim3(16, 5, 256), 256, 0, stream>>>(trees, X0);
    prepW_kernel<<<480 * 256 / 256, 256, 0, stream>>>(Wc1, Wfc1, 480, 256, 160, 1);
    prepW_kernel<<<160 * 256 / 256, 256, 0, stream>>>(Wm1, Wfm1, 160, 256, 160, 0);
    prepW_kernel<<<768 * 128 / 256, 256, 0, stream>>>(Wc2, Wfc2, 768, 128, 256, 1);
    prepW_kernel<<<256 * 128 / 256, 256, 0, stream>>>(Wm2, Wfm2, 256, 128, 256, 0);
    prepW_kernel<<<384 * 64 / 256, 256, 0, stream>>>(Wc3, Wfc3, 384, 64, 128, 1);
    prepW_kernel<<<128 * 64 / 256, 256, 0, stream>>>(Wm3, Wfm3, 128, 64, 128, 0);

    convA_kernel<160, 256, 160><<<dim3(16, 256), 256, 0, stream>>>(X0, indexes, Wfc1, bc1, A1, part);
    reduce_stats_kernel<<<256, 64, 0, stream>>>(part, stats, 16, 262144.f);
    mixB_kernel<160, 256><<<dim3(16, 256), 256, 0, stream>>>(X0, Wfm1, bm1, A1, stats);

    convA_kernel<256, 128, 128><<<dim3(16, 256), 256, 0, stream>>>(A1, indexes, Wfc2, bc2, A2, part);
    reduce_stats_kernel<<<256, 64, 0, stream>>>(part, stats, 16, 131072.f);
    mixB_kernel<256, 128><<<dim3(16, 256), 256, 0, stream>>>(A1, Wfm2, bm2, A2, stats);

    convA_kernel<128, 64, 128><<<dim3(16, 256), 256, 0, stream>>>(A2, indexes, Wfc3, bc3, A3, part);
    reduce_stats_kernel<<<256, 64, 0, stream>>>(part, stats, 16, 65536.f);
    mixB_kernel<128, 64><<<dim3(16, 256), 256, 0, stream>>>(A2, Wfm3, bm3, A3, stats);

    final_kernel<<<256, 256, 0, stream>>>(A3, nodes, W1, b1, W2, b2, out);
}

// Round 5
// 594.880 us; speedup vs baseline: 1.2423x; 1.0723x over previous
//
#include <hip/hip_runtime.h>
#include <stdint.h>

using f16 = _Float16;
typedef __attribute__((ext_vector_type(8))) f16 f16x8;
typedef __attribute__((ext_vector_type(4))) float f32x4;

constexpr int N = 1024;

__device__ __forceinline__ float leaky(float v) { return v >= 0.f ? v : 0.01f * v; }

__device__ __forceinline__ void dma16(const void* g, void* l) {
    __builtin_amdgcn_global_load_lds(
        (const __attribute__((address_space(1))) uint32_t*)g,
        (__attribute__((address_space(3))) uint32_t*)l, 16, 0, 0);
}

template<int A> __device__ __forceinline__ void wait_vm() {
    asm volatile("s_waitcnt vmcnt(%0)" :: "n"(A) : "memory");
}

// ---------------------------------------------------------------------------
// Phase A: BinaryTreeConv  Yc^T[n][o] = sum_kap Xg[n][kap] * Wfc[kap][o] + bc
// Tile: 64 nodes x CO, 4 waves (2 n-groups x 2 o-groups). CK=96 K-chunks,
// TRIPLE buffered with TRUE distance-2 prefetch: stage(t+2) issued during
// compute(t). The vmcnt allowance accounts for the WPC W-fragment global
// loads interleaved in the FIFO, so each wait retires exactly stage(t).
// Rotation swizzle keeps ds_read_b128 fragments <=2-way bank aliased.
// ---------------------------------------------------------------------------
template<int CI, int CO, int CK>
__global__ __launch_bounds__(256) void convA_kernel(
    const f16* __restrict__ X, const int* __restrict__ idx,
    const f16* __restrict__ Wf, const float* __restrict__ bc,
    f16* __restrict__ yc, float2* __restrict__ part)
{
    constexpr int T = 3 * CI / CK;       // chunks
    constexpr int U = CO / 16, UW = CO / 32;
    constexpr int S = CK / 8;            // 16B slots per row
    constexpr int P = 2 * CK;            // row pitch bytes
    constexpr int NG = CK / 32;          // dma16 per thread per chunk
    constexpr int WPC = (CK / 32) * UW;  // W-fragment VMEM loads per wave per chunk
    constexpr int BUF = 64 * CK * 2;     // bytes per buffer
    static_assert(CK % 32 == 0 && (3 * CI) % CK == 0 && T >= 4, "geometry");

    __shared__ alignas(16) f16 stage[3 * 64 * CK];
    __shared__ float redu[8];

    const int tid = threadIdx.x;
    const int w = tid >> 6, l = tid & 63;
    const int wn = w & 1, wo = w >> 1;
    const int n0 = blockIdx.x * 64;
    const int b = blockIdx.y;

    // granule geometry + hoisted gather indices (segment-split arrays so all
    // indexing is compile-time -> registers, runtime seg chosen by cndmask)
    int kapb[NG];
    int rows0[NG], rows1[NG], rows2[NG];
    {
        const int ib = b * 3 * N + 3 * n0;
        #pragma unroll
        for (int r = 0; r < NG; ++r) {
            int G = w * (NG * 64) + r * 64 + l;
            int rrow = G / S;
            int cs = G % S - (rrow & 7);
            if (cs < 0) cs += S;
            kapb[r] = cs * 8;
            rows0[r] = idx[ib + 3 * rrow + 0];
            rows1[r] = idx[ib + 3 * rrow + 1];
            rows2[r] = idx[ib + 3 * rrow + 2];
        }
    }
    const char* xb = (const char*)(X + (size_t)b * N * CI);
    char* sbase = (char*)stage;

    auto stage_chunk = [&](int t) {      // t is compile-time at every call site
        char* dstb = sbase + (t % 3) * BUF + w * (NG * 1024);
        #pragma unroll
        for (int r = 0; r < NG; ++r) {
            int kap = t * CK + kapb[r];
            int seg = (kap >= 2 * CI) ? 2 : (kap >= CI) ? 1 : 0;
            int cof = kap - seg * CI;
            int row = seg == 0 ? rows0[r] : (seg == 1 ? rows1[r] : rows2[r]);
            dma16(xb + ((size_t)row * CI + cof) * 2, dstb + r * 1024);
        }
    };

    int rowb[2], rot[2];
    #pragma unroll
    for (int rt = 0; rt < 2; ++rt) {
        int rr = 32 * wn + 16 * rt + (l & 15);
        rowb[rt] = rr * P;
        rot[rt] = (l >> 4) + (rr & 7);
    }

    f32x4 acc[2][UW] = {};
    stage_chunk(0);
    stage_chunk(1);

    #pragma unroll
    for (int t = 0; t < T; ++t) {
        if (t + 2 < T) stage_chunk(t + 2);
        // retire exactly stage(t): allowance counts stages + W loads issued after it
        if (t == 0)            wait_vm<2 * NG>();
        else if (t == 1)       wait_vm<2 * NG + WPC>();
        else if (t + 2 < T)    wait_vm<2 * (NG + WPC)>();
        else if (t + 2 == T)   wait_vm<NG + 2 * WPC>();
        else                   wait_vm<0>();
        __builtin_amdgcn_s_barrier();
        __builtin_amdgcn_sched_barrier(0);
        const char* sb = sbase + (t % 3) * BUF;
        #pragma unroll
        for (int s = 0; s < CK / 32; ++s) {
            f16x8 a0, a1;
            {
                int sl = 4 * s + rot[0]; if (sl >= S) sl -= S;
                a0 = *(const f16x8*)(sb + rowb[0] + sl * 16);
            }
            {
                int sl = 4 * s + rot[1]; if (sl >= S) sl -= S;
                a1 = *(const f16x8*)(sb + rowb[1] + sl * 16);
            }
            const int skk = t * (CK / 32) + s;
            #pragma unroll
            for (int uu = 0; uu < UW; ++uu) {
                f16x8 wv = *(const f16x8*)(Wf + (((size_t)skk * U + wo * UW + uu) * 64 + l) * 8);
                acc[0][uu] = __builtin_amdgcn_mfma_f32_16x16x32_f16(a0, wv, acc[0][uu], 0, 0, 0);
                acc[1][uu] = __builtin_amdgcn_mfma_f32_16x16x32_f16(a1, wv, acc[1][uu], 0, 0, 0);
            }
        }
        __builtin_amdgcn_s_barrier();    // all reads of buf t%3 done before reuse
    }

    // epilogue: bias, store f16, per-tree stats partials
    float p1 = 0.f, p2 = 0.f;
    #pragma unroll
    for (int rt = 0; rt < 2; ++rt) {
        #pragma unroll
        for (int uu = 0; uu < UW; ++uu) {
            int o = wo * (CO / 2) + uu * 16 + (l & 15);
            float bcv = bc[o];
            size_t rb = ((size_t)b * N + (n0 + 32 * wn + 16 * rt + 4 * (l >> 4))) * CO + o;
            #pragma unroll
            for (int j = 0; j < 4; ++j) {
                float v = acc[rt][uu][j] + bcv;
                yc[rb + (size_t)j * CO] = (f16)v;
                p1 += v; p2 += v * v;
            }
        }
    }
    #pragma unroll
    for (int m = 32; m; m >>= 1) { p1 += __shfl_xor(p1, m); p2 += __shfl_xor(p2, m); }
    if (l == 0) { redu[w * 2] = p1; redu[w * 2 + 1] = p2; }
    __syncthreads();
    if (tid == 0)
        part[(size_t)b * 16 + blockIdx.x] =
            make_float2(redu[0] + redu[2] + redu[4] + redu[6],
                        redu[1] + redu[3] + redu[5] + redu[7]);
}

__global__ __launch_bounds__(64) void reduce_stats_kernel(
    const float2* __restrict__ part, float2* __restrict__ stats, int nparts, float Mf)
{
    int b = blockIdx.x;
    float s1 = 0.f, s2 = 0.f;
    for (int i = threadIdx.x; i < nparts; i += 64) {
        float2 p = part[(size_t)b * nparts + i];
        s1 += p.x; s2 += p.y;
    }
    #pragma unroll
    for (int m = 32; m; m >>= 1) { s1 += __shfl_xor(s1, m); s2 += __shfl_xor(s2, m); }
    if (threadIdx.x == 0) {
        float mu = s1 / Mf;
        float var = (s2 - s1 * s1 / Mf) / (Mf - 1.f);   // ddof = 1
        var = fmaxf(var, 0.f);
        stats[b] = make_float2(mu, 1.f / (sqrtf(var) + 1e-5f));
    }
}

// ---------------------------------------------------------------------------
// Phase B: ChannelMixer GEMM (K = CI, identity rows, no gather); whole K fits
// LDS -> single staging pass, ONE barrier, then pure MFMA. TreeLayerNorm +
// leaky fused into the epilogue: x = leaky(ym + (yc-mu)*inv), in place.
// ---------------------------------------------------------------------------
template<int CI, int CO>
__global__ __launch_bounds__(256) void mixB_kernel(
    const f16* __restrict__ X, const f16* __restrict__ Wf, const float* __restrict__ bm,
    f16* __restrict__ y, const float2* __restrict__ stats)
{
    constexpr int U = CO / 16, UW = CO / 32;
    constexpr int S = CI / 8;
    constexpr int P = 2 * CI;
    constexpr int NG = CI / 32;

    __shared__ alignas(16) f16 stage[64 * CI];

    const int tid = threadIdx.x;
    const int w = tid >> 6, l = tid & 63;
    const int wn = w & 1, wo = w >> 1;
    const int n0 = blockIdx.x * 64;
    const int b = blockIdx.y;

    const char* xb = (const char*)(X + (size_t)b * N * CI);
    char* sbase = (char*)stage;
    char* dstb = sbase + w * (NG * 1024);

    #pragma unroll
    for (int r = 0; r < NG; ++r) {
        int G = w * (NG * 64) + r * 64 + l;
        int rr = G / S;
        int cs = G % S - (rr & 7);
        if (cs < 0) cs += S;
        dma16(xb + ((size_t)(n0 + rr) * CI + cs * 8) * 2, dstb + r * 1024);
    }

    int rowb[2], rot[2];
    #pragma unroll
    for (int rt = 0; rt < 2; ++rt) {
        int rr = 32 * wn + 16 * rt + (l & 15);
        rowb[rt] = rr * P;
        rot[rt] = (l >> 4) + (rr & 7);
    }

    f32x4 acc[2][UW] = {};
    __syncthreads();

    #pragma unroll
    for (int s = 0; s < CI / 32; ++s) {
        f16x8 a0, a1;
        {
            int sl = 4 * s + rot[0]; if (sl >= S) sl -= S;
            a0 = *(const f16x8*)(sbase + rowb[0] + sl * 16);
        }
        {
            int sl = 4 * s + rot[1]; if (sl >= S) sl -= S;
            a1 = *(const f16x8*)(sbase + rowb[1] + sl * 16);
        }
        #pragma unroll
        for (int uu = 0; uu < UW; ++uu) {
            f16x8 wv = *(const f16x8*)(Wf + (((size_t)s * U + wo * UW + uu) * 64 + l) * 8);
            acc[0][uu] = __builtin_amdgcn_mfma_f32_16x16x32_f16(a0, wv, acc[0][uu], 0, 0, 0);
            acc[1][uu] = __builtin_amdgcn_mfma_f32_16x16x32_f16(a1, wv, acc[1][uu], 0, 0, 0);
        }
    }

    const float2 st = stats[b];
    #pragma unroll
    for (int rt = 0; rt < 2; ++rt) {
        #pragma unroll
        for (int uu = 0; uu < UW; ++uu) {
            int o = wo * (CO / 2) + uu * 16 + (l & 15);
            float bmv = bm[o];
            size_t rb = ((size_t)b * N + (n0 + 32 * wn + 16 * rt + 4 * (l >> 4))) * CO + o;
            #pragma unroll
            for (int j = 0; j < 4; ++j) {
                size_t off = rb + (size_t)j * CO;
                float ycv = (float)y[off];
                float v = acc[rt][uu][j] + bmv + (ycv - st.x) * st.y;
                y[off] = (f16)leaky(v);
            }
        }
    }
}

// fp32 [B][160][N] -> f16 [B][N][160]
__global__ __launch_bounds__(256) void transpose_kernel(
    const float* __restrict__ trees, f16* __restrict__ X0)
{
    __shared__ f16 tile[32][66];
    int b = blockIdx.z, c0 = blockIdx.y * 32, n0 = blockIdx.x * 64;
    int tid = threadIdx.x;
    int nl = tid & 63, c4 = tid >> 6;
    #pragma unroll
    for (int cc = 0; cc < 8; ++cc) {
        int c = c4 * 8 + cc;
        tile[c][nl] = (f16)trees[((size_t)b * 160 + c0 + c) * N + n0 + nl];
    }
    __syncthreads();
    int nn = tid >> 2, gc = tid & 3;
    f16x8 pack;
    #pragma unroll
    for (int e = 0; e < 8; ++e) pack[e] = tile[gc * 8 + e][nn];
    *(f16x8*)(X0 + ((size_t)b * N + n0 + nn) * 160 + c0 + gc * 8) = pack;
}

// weights -> fragment-ready f16 layout: elem ((t*U+u)*64+l)*8+j  holds
// W[kap = 32t+8*(l>>4)+j][o = 16u+(l&15)], kappa-order kap = k*CI + c.
__global__ __launch_bounds__(256) void prepW_kernel(
    const float* __restrict__ Wsrc, f16* __restrict__ out,
    int K, int CO, int CI, int isconv)
{
    int e = blockIdx.x * 256 + threadIdx.x;
    if (e >= K * CO) return;
    int j = e & 7, l = (e >> 3) & 63, r = e >> 9;
    int U = CO / 16;
    int u = r % U, t = r / U;
    int kap = 32 * t + 8 * (l >> 4) + j;
    int o = 16 * u + (l & 15);
    float v = isconv ? Wsrc[((size_t)o * CI + (kap % CI)) * 3 + kap / CI]
                     : Wsrc[(size_t)o * CI + kap];
    out[e] = (f16)v;
}

// masked max-pool over valid nodes + 64->32->1 MLP; x3 is [b][n][64] f16.
__global__ __launch_bounds__(256) void final_kernel(
    const f16* __restrict__ x3, const int* __restrict__ nodes,
    const float* __restrict__ W1, const float* __restrict__ b1,
    const float* __restrict__ W2, const float* __restrict__ b2,
    float* __restrict__ out)
{
    int b = blockIdx.x, tid = threadIdx.x;
    int o = tid & 63, r = tid >> 6;
    int nv = nodes[b];
    const f16* p = x3 + (size_t)b * N * 64 + o;
    float mx = -3.4e38f;
    for (int n = r; n < nv; n += 4) mx = fmaxf(mx, (float)p[(size_t)n * 64]);
    __shared__ float pool[4][64];
    __shared__ float pooled[64], hbuf[32];
    pool[r][o] = mx;
    __syncthreads();
    if (tid < 64) pooled[tid] = fmaxf(fmaxf(pool[0][tid], pool[1][tid]),
                                      fmaxf(pool[2][tid], pool[3][tid]));
    __syncthreads();
    if (tid < 32) {
        float h = b1[tid];
        #pragma unroll 8
        for (int oo = 0; oo < 64; ++oo) h += pooled[oo] * W1[oo * 32 + tid];
        hbuf[tid] = leaky(h);
    }
    __syncthreads();
    if (tid == 0) {
        float rr = b2[0];
        for (int jj = 0; jj < 32; ++jj) rr += hbuf[jj] * W2[jj];
        out[b] = rr;
    }
}

extern "C" void kernel_launch(void* const* d_in, const int* in_sizes, int n_in,
                              void* d_out, int out_size, void* d_ws, size_t ws_size,
                              hipStream_t stream)
{
    (void)in_sizes; (void)n_in; (void)out_size; (void)ws_size;
    const float* trees = (const float*)d_in[0];
    const int* indexes = (const int*)d_in[1];
    const int* nodes   = (const int*)d_in[2];
    const float* Wc1 = (const float*)d_in[3];
    const float* bc1 = (const float*)d_in[4];
    const float* Wm1 = (const float*)d_in[5];
    const float* bm1 = (const float*)d_in[6];
    const float* Wc2 = (const float*)d_in[7];
    const float* bc2 = (const float*)d_in[8];
    const float* Wm2 = (const float*)d_in[9];
    const float* bm2 = (const float*)d_in[10];
    const float* Wc3 = (const float*)d_in[11];
    const float* bc3 = (const float*)d_in[12];
    const float* Wm3 = (const float*)d_in[13];
    const float* bm3 = (const float*)d_in[14];
    const float* W1 = (const float*)d_in[15];
    const float* b1 = (const float*)d_in[16];
    const float* W2 = (const float*)d_in[17];
    const float* b2 = (const float*)d_in[18];
    float* out = (float*)d_out;

    // ws layout:
    //   [0, 83886080)            X0 [B][N][160] f16      -> later yc2/x2 (67MB)
    //   [83886080, 218103808)    yc1/x1 [B][N][256] f16  -> later yc3/x3 (33.5MB)
    //   [218103808, ...)         Wfrags, parts, stats
    char* ws = (char*)d_ws;
    f16* X0 = (f16*)ws;
    f16* A1 = (f16*)(ws + 83886080);
    f16* A2 = (f16*)ws;
    f16* A3 = A1;
    size_t toff = 218103808;
    f16* Wfc1 = (f16*)(ws + toff); toff += (size_t)480 * 256 * 2;
    f16* Wfm1 = (f16*)(ws + toff); toff += (size_t)160 * 256 * 2;
    f16* Wfc2 = (f16*)(ws + toff); toff += (size_t)768 * 128 * 2;
    f16* Wfm2 = (f16*)(ws + toff); toff += (size_t)256 * 128 * 2;
    f16* Wfc3 = (f16*)(ws + toff); toff += (size_t)384 * 64 * 2;
    f16* Wfm3 = (f16*)(ws + toff); toff += (size_t)128 * 64 * 2;
    float2* part  = (float2*)(ws + toff); toff += (size_t)256 * 16 * 8;
    float2* stats = (float2*)(ws + toff);

    transpose_kernel<<<dim3(16, 5, 256), 256, 0, stream>>>(trees, X0);
    prepW_kernel<<<480 * 256 / 256, 256, 0, stream>>>(Wc1, Wfc1, 480, 256, 160, 1);
    prepW_kernel<<<160 * 256 / 256, 256, 0, stream>>>(Wm1, Wfm1, 160, 256, 160, 0);
    prepW_kernel<<<768 * 128 / 256, 256, 0, stream>>>(Wc2, Wfc2, 768, 128, 256, 1);
    prepW_kernel<<<256 * 128 / 256, 256, 0, stream>>>(Wm2, Wfm2, 256, 128, 256, 0);
    prepW_kernel<<<384 * 64 / 256, 256, 0, stream>>>(Wc3, Wfc3, 384, 64, 128, 1);
    prepW_kernel<<<128 * 64 / 256, 256, 0, stream>>>(Wm3, Wfm3, 128, 64, 128, 0);

    convA_kernel<160, 256, 96><<<dim3(16, 256), 256, 0, stream>>>(X0, indexes, Wfc1, bc1, A1, part);
    reduce_stats_kernel<<<256, 64, 0, stream>>>(part, stats, 16, 262144.f);
    mixB_kernel<160, 256><<<dim3(16, 256), 256, 0, stream>>>(X0, Wfm1, bm1, A1, stats);

    convA_kernel<256, 128, 96><<<dim3(16, 256), 256, 0, stream>>>(A1, indexes, Wfc2, bc2, A2, part);
    reduce_stats_kernel<<<256, 64, 0, stream>>>(part, stats, 16, 131072.f);
    mixB_kernel<256, 128><<<dim3(16, 256), 256, 0, stream>>>(A1, Wfm2, bm2, A2, stats);

    convA_kernel<128, 64, 96><<<dim3(16, 256), 256, 0, stream>>>(A2, indexes, Wfc3, bc3, A3, part);
    reduce_stats_kernel<<<256, 64, 0, stream>>>(part, stats, 16, 65536.f);
    mixB_kernel<128, 64><<<dim3(16, 256), 256, 0, stream>>>(A2, Wfm3, bm3, A3, stats);

    final_kernel<<<256, 256, 0, stream>>>(A3, nodes, W1, b1, W2, b2, out);
}